// Round 8
// baseline (173.959 us; speedup 1.0000x reference)
//
#include <hip/hip_runtime.h>
#include <hip/hip_bf16.h>

// Block-causal GQA attention, T=2048 HQ=16 HKV=4 D=128, block 256.
// q_ranges/k_ranges deterministic: q block r attends k < (r+1)*256.
// LDS-FREE design: 1 wave per (32 q-rows, head, 256-KV chunk), 32x32x16 MFMA,
// everything in registers, no barriers. 4608 uniform waves x 8 KV-tiles of 32.
// Partials (u32-packed bf16, coalesced) + stats -> reduce kernel merges.
#define T_   2048
#define HQ_  16
#define HKV_ 4
#define D_   128

typedef float f32x4  __attribute__((ext_vector_type(4)));
typedef float f32x16 __attribute__((ext_vector_type(16)));
typedef __bf16 bf16x8 __attribute__((ext_vector_type(8)));
typedef unsigned short u16;
typedef unsigned short u16x8 __attribute__((ext_vector_type(8)));
typedef unsigned int u32;
typedef u32 u32x4 __attribute__((ext_vector_type(4)));
typedef unsigned long long u64;

__device__ __forceinline__ u16 f2bf(float f) {
  u32 u = __builtin_bit_cast(u32, f);
  u += 0x7FFFu + ((u >> 16) & 1u);   // RNE bf16
  return (u16)(u >> 16);
}
__device__ __forceinline__ float bf2f(u16 v) {
  return __builtin_bit_cast(float, (u32)v << 16);
}

// ---------------- prep (unchanged from r4/r6/r7 — passed) -------------------
#define QK_BLOCKS 1280
__global__ __launch_bounds__(256) void prep_all(
    const float* __restrict__ q, const float* __restrict__ k,
    const float* __restrict__ v, const float* __restrict__ ct,
    const float* __restrict__ st,
    u16* __restrict__ qr, u16* __restrict__ kr, u16* __restrict__ vt)
{
  __shared__ __attribute__((aligned(16))) char Lv[32 * 144];
  const int tid = threadIdx.x;
  const int bid = blockIdx.x;
  if (bid < QK_BLOCKS) {
    const float scale = 0.08838834764831845f; // 1/sqrt(128)
    const int NQT = T_ * HQ_ * 8;
    int gid = bid * 256 + tid;
    if (gid < NQT) {
      int j0 = (gid & 7) * 8;
      int h  = (gid >> 3) & 15;
      int t  = gid >> 7;
      const float* base = q + ((size_t)t * HQ_ + h) * D_;
      const float* cb = ct + t * 64 + j0;
      const float* sb = st + t * 64 + j0;
      u16 lo[8], hi[8];
#pragma unroll
      for (int e = 0; e < 8; ++e) {
        float x1 = base[j0 + e], x2 = base[j0 + 64 + e];
        float c = cb[e], s = sb[e];
        lo[e] = f2bf((x1 * c - x2 * s) * scale);
        hi[e] = f2bf((x2 * c + x1 * s) * scale);
      }
      u16* orow = qr + ((size_t)h * T_ + t) * D_;
      *reinterpret_cast<u16x8*>(orow + j0)      = *reinterpret_cast<u16x8*>(lo);
      *reinterpret_cast<u16x8*>(orow + 64 + j0) = *reinterpret_cast<u16x8*>(hi);
    } else {
      int th = gid - NQT;
      int j0 = (th & 7) * 8;
      int hh = (th >> 3) & 3;
      int t  = th >> 5;
      const float* base = k + ((size_t)t * HKV_ + hh) * D_;
      const float* cb = ct + t * 64 + j0;
      const float* sb = st + t * 64 + j0;
      u16 lo[8], hi[8];
#pragma unroll
      for (int e = 0; e < 8; ++e) {
        float x1 = base[j0 + e], x2 = base[j0 + 64 + e];
        float c = cb[e], s = sb[e];
        lo[e] = f2bf(x1 * c - x2 * s);
        hi[e] = f2bf(x2 * c + x1 * s);
      }
      u16* orow = kr + ((size_t)hh * T_ + t) * D_;
      *reinterpret_cast<u16x8*>(orow + j0)      = *reinterpret_cast<u16x8*>(lo);
      *reinterpret_cast<u16x8*>(orow + 64 + j0) = *reinterpret_cast<u16x8*>(hi);
    }
  } else {
    int vbid = bid - QK_BLOCKS;
    int hh = vbid & 3;
    int t0 = ((vbid >> 2) & 31) * 64;
    int d0 = (vbid >> 7) * 32;
    {
      int r  = tid >> 2;
      int dg = tid & 3;
      const float* vrow = v + ((size_t)(t0 + r) * HKV_ + hh) * D_ + d0 + dg * 8;
      float4 f0 = *reinterpret_cast<const float4*>(vrow);
      float4 f1 = *reinterpret_cast<const float4*>(vrow + 4);
      float fv[8] = {f0.x, f0.y, f0.z, f0.w, f1.x, f1.y, f1.z, f1.w};
#pragma unroll
      for (int e = 0; e < 8; ++e)
        *reinterpret_cast<u16*>(Lv + (dg * 8 + e) * 144 + r * 2) = f2bf(fv[e]);
    }
    __syncthreads();
    {
      int dl = tid >> 3;
      int c0 = (tid & 7) * 16;
      u16x8 val = *reinterpret_cast<const u16x8*>(Lv + dl * 144 + c0);
      u16* orow = vt + ((size_t)(hh * D_ + d0 + dl)) * T_ + t0 + (c0 >> 1);
      *reinterpret_cast<u16x8*>(orow) = val;
    }
  }
}

// ---------------- flash attention: 1 wave, 32x32 MFMA, no LDS ---------------
// slot = hkv*1152 + pair*4 + hl; pair = 4g(g+1) + qq*(g+1) + ck, qb32=8g+qq.
// Per wave: 8 tiles of 32 KV. S^T = K*Q (C/D: col=q=l&31,
// row=kk=(reg&3)+8*(reg>>2)+4*(l>>5)); O^T = V^T * P^T.
__global__ __launch_bounds__(64, 2) void attn_fwd(
    const u16* __restrict__ qr, const u16* __restrict__ kr,
    const u16* __restrict__ vt, u32* __restrict__ part,
    float* __restrict__ stats)
{
  const int lane = threadIdx.x;
  const int ql = lane & 31;
  const int hi = lane >> 5;

  // decode slot (wave-uniform scalar math)
  const int bid = blockIdx.x;               // 4608 = 8 XCD x 576
  const int slot = (bid & 7) * 576 + (bid >> 3);
  const int hkv = slot / 1152;
  const int r1  = slot - hkv * 1152;
  const int pair = r1 >> 2, hl = r1 & 3;
  int g = 0;
  while (4 * (g + 1) * (g + 2) <= pair) ++g;
  const int cb = g + 1;
  const int r  = pair - 4 * g * (g + 1);
  const int qq = r / cb, ck = r - qq * cb;
  const int qb32 = 8 * g + qq;
  const int h  = hkv * 4 + hl;
  const int q0 = qb32 * 32;
  const int kvb = ck * 256;

  // Q B-frags: lane holds Q[q=q0+ql][kb*16 + 8*hi + i]
  bf16x8 qf[8];
  {
    const u16* qrow = qr + ((size_t)h * T_ + q0 + ql) * D_ + hi * 8;
#pragma unroll
    for (int kb = 0; kb < 8; ++kb)
      qf[kb] = *reinterpret_cast<const bf16x8*>(qrow + kb * 16);
  }

  const u16* krow = kr + ((size_t)hkv * T_ + kvb + ql) * D_ + hi * 8;
  const u16* vrow = vt + ((size_t)hkv * D_ + ql) * T_ + kvb + hi * 8;

  f32x16 accO[4] = {};
  float mrun = -1e30f, lrun = 0.f;

#pragma unroll
  for (int t = 0; t < 8; ++t) {
    // ---- load K A-frags (row=kk=ql, k=8hi+i per 16-k chunk) ----
    const u16* kt = krow + (size_t)t * 32 * D_;
    bf16x8 kf[8];
#pragma unroll
    for (int kb = 0; kb < 8; ++kb)
      kf[kb] = *reinterpret_cast<const bf16x8*>(kt + kb * 16);
    // ---- load V A-frags early (row=d=c*32+ql, k=kk 16-half) ----
    bf16x8 vf[8];
#pragma unroll
    for (int c = 0; c < 4; ++c)
#pragma unroll
      for (int hf = 0; hf < 2; ++hf)
        vf[c * 2 + hf] = *reinterpret_cast<const bf16x8*>(
            vrow + (size_t)c * 32 * T_ + t * 32 + hf * 16);

    // ---- QK^T ----
    f32x16 s = {};
    __builtin_amdgcn_s_setprio(1);
#pragma unroll
    for (int kb = 0; kb < 8; ++kb)
      s = __builtin_amdgcn_mfma_f32_32x32x16_bf16(kf[kb], qf[kb], s, 0, 0, 0);
    __builtin_amdgcn_s_setprio(0);

    // ---- softmax per q (=ql); kk halves live in lane and lane^32 ----
    float t0m = fmaxf(fmaxf(fmaxf(s[0], s[1]), fmaxf(s[2], s[3])),
                      fmaxf(fmaxf(s[4], s[5]), fmaxf(s[6], s[7])));
    float t1m = fmaxf(fmaxf(fmaxf(s[8], s[9]), fmaxf(s[10], s[11])),
                      fmaxf(fmaxf(s[12], s[13]), fmaxf(s[14], s[15])));
    float tmax = fmaxf(t0m, t1m);
    tmax = fmaxf(tmax, __shfl_xor(tmax, 32));
    float mnew  = fmaxf(mrun, tmax);
    float alpha = __expf(mrun - mnew);
    float p[16];
    float psum = 0.f;
#pragma unroll
    for (int i = 0; i < 16; ++i) { p[i] = __expf(s[i] - mnew); psum += p[i]; }
    psum += __shfl_xor(psum, 32);
    lrun = lrun * alpha + psum;
    mrun = mnew;
#pragma unroll
    for (int c = 0; c < 4; ++c)
#pragma unroll
      for (int i = 0; i < 16; ++i) accO[c][i] *= alpha;

    // ---- pack P -> bf16 u32 pairs; exchange lane<->lane^32 ----
    // P[j] packs regs (2j,2j+1): kk = (2j&3)+8*(j>>1)+4*hi, +1
    u32 P[8], X[8];
#pragma unroll
    for (int j = 0; j < 8; ++j) {
      u32 w;
      asm("v_cvt_pk_bf16_f32 %0, %1, %2" : "=v"(w) : "v"(p[2 * j]), "v"(p[2 * j + 1]));
      P[j] = w;
    }
#pragma unroll
    for (int j = 0; j < 8; ++j) X[j] = (u32)__shfl_xor((int)P[j], 32);
    // B-frag kk-half0: hi0 lane k=0..7 -> {P0,P1,X0,X1}; hi1 k=8..15 -> {X2,X3,P2,P3}
    u32x4 f0 = { hi ? X[2] : P[0], hi ? X[3] : P[1],
                 hi ? P[2] : X[0], hi ? P[3] : X[1] };
    // kk-half1: hi0 k=16..23 -> {P4,P5,X4,X5}; hi1 k=24..31 -> {X6,X7,P6,P7}
    u32x4 f1 = { hi ? X[6] : P[4], hi ? X[7] : P[5],
                 hi ? P[6] : X[4], hi ? P[7] : X[5] };
    bf16x8 pf0 = __builtin_bit_cast(bf16x8, f0);
    bf16x8 pf1 = __builtin_bit_cast(bf16x8, f1);

    // ---- PV: O^T[d-chunk][q] += V^T * P^T ----
    __builtin_amdgcn_s_setprio(1);
#pragma unroll
    for (int c = 0; c < 4; ++c) {
      accO[c] = __builtin_amdgcn_mfma_f32_32x32x16_bf16(vf[c * 2],     pf0, accO[c], 0, 0, 0);
      accO[c] = __builtin_amdgcn_mfma_f32_32x32x16_bf16(vf[c * 2 + 1], pf1, accO[c], 0, 0, 0);
    }
    __builtin_amdgcn_s_setprio(0);
  }

  // ---- epilogue: partial O^T (unnormalized) -> u32-packed bf16, coalesced --
  // lane reg: d = c*32 + (reg&3) + 8*(reg>>2) + 4*hi, q = ql.
  u32* pp = part + (size_t)slot * 2048;
#pragma unroll
  for (int c = 0; c < 4; ++c)
#pragma unroll
    for (int j = 0; j < 8; ++j) {
      u32 w;
      asm("v_cvt_pk_bf16_f32 %0, %1, %2"
          : "=v"(w) : "v"(accO[c][2 * j]), "v"(accO[c][2 * j + 1]));
      int dp = c * 16 + (j & 1) + 4 * (j >> 1) + 2 * hi;  // = d/2
      pp[dp * 32 + ql] = w;
    }
  if (hi == 0) {
    float2 ml = make_float2(mrun, lrun);
    *reinterpret_cast<float2*>(stats + (size_t)slot * 64 + ql * 2) = ml;
  }
}

// ---------------- reduce: merge <=8 chunk-partials per (qb32,h) -------------
__global__ __launch_bounds__(256) void reduce_k(
    const u32* __restrict__ part, const float* __restrict__ stats,
    float* __restrict__ out)
{
  const int bid  = blockIdx.x;        // 1024 = 64 qb32 x 16 h
  const int qb32 = bid >> 4;
  const int h    = bid & 15;
  const int hkv  = h >> 2, hl = h & 3;
  const int g    = qb32 >> 3, qq = qb32 & 7;
  const int cb   = g + 1;
  const int pairbase = 4 * g * (g + 1) + qq * cb;

  const int t  = threadIdx.x;
  const int q  = t & 31;
  const int dg = t >> 5;              // 0..7, d-range dg*16..+15

  float m[8], l[8];
  float M = -1e30f;
#pragma unroll
  for (int ck = 0; ck < 8; ++ck)
    if (ck < cb) {
      int slot = hkv * 1152 + (pairbase + ck) * 4 + hl;
      float2 ml = *reinterpret_cast<const float2*>(stats + (size_t)slot * 64 + q * 2);
      m[ck] = ml.x; l[ck] = ml.y;
      M = fmaxf(M, m[ck]);
    }
  float L = 0.f, w[8];
#pragma unroll
  for (int ck = 0; ck < 8; ++ck)
    if (ck < cb) { w[ck] = __expf(m[ck] - M); L += w[ck] * l[ck]; }
  float inv = 1.f / L;

  float acc[16];
#pragma unroll
  for (int e = 0; e < 16; ++e) acc[e] = 0.f;
#pragma unroll
  for (int ck = 0; ck < 8; ++ck)
    if (ck < cb) {
      int slot = hkv * 1152 + (pairbase + ck) * 4 + hl;
      const u32* pp = part + (size_t)slot * 2048 + dg * 256 + q;
      float wc = w[ck];
#pragma unroll
      for (int j = 0; j < 8; ++j) {
        u32 v = pp[j * 32];
        acc[2 * j]     += wc * bf2f((u16)(v & 0xFFFF));
        acc[2 * j + 1] += wc * bf2f((u16)(v >> 16));
      }
    }

  float* orow = out + ((size_t)(qb32 * 32 + q) * HQ_ + h) * D_ + dg * 16;
#pragma unroll
  for (int j = 0; j < 4; ++j) {
    f32x4 o;
    o[0] = acc[4 * j + 0] * inv; o[1] = acc[4 * j + 1] * inv;
    o[2] = acc[4 * j + 2] * inv; o[3] = acc[4 * j + 3] * inv;
    *reinterpret_cast<f32x4*>(orow + 4 * j) = o;
  }
}

extern "C" void kernel_launch(void* const* d_in, const int* in_sizes, int n_in,
                              void* d_out, int out_size, void* d_ws, size_t ws_size,
                              hipStream_t stream) {
  const float* q  = (const float*)d_in[0];
  const float* k  = (const float*)d_in[1];
  const float* v  = (const float*)d_in[2];
  const float* ct = (const float*)d_in[3];
  const float* st = (const float*)d_in[4];

  u16* qr = (u16*)d_ws;                            // 8 MB   [h][t][128]
  u16* kr = qr + (size_t)T_ * HQ_ * D_;            // 2 MB   [hkv][t][128]
  u16* vt = kr + (size_t)T_ * HKV_ * D_;           // 2 MB   [hkv][d][t]
  u32* part = (u32*)(vt + (size_t)T_ * HKV_ * D_); // 4608*8KB = 37.7 MB
  float* stats = (float*)(part + (size_t)4608 * 2048); // 4608*256B = 1.2 MB
  float* out = (float*)d_out;

  prep_all<<<QK_BLOCKS + 512, 256, 0, stream>>>(q, k, v, ct, st, qr, kr, vt);
  attn_fwd<<<4608, 64, 0, stream>>>(qr, kr, vt, part, stats);
  reduce_k<<<1024, 256, 0, stream>>>(part, stats, out);
}